// Round 2
// baseline (548.930 us; speedup 1.0000x reference)
//
#include <hip/hip_runtime.h>
#include <hip/hip_bf16.h>

#define NB 16
#define CIN 768
#define HC 8
#define LT 4160

// ---------------------------------------------------------------------------
// K1: x(B,LT,768) fp32 @ W(768,8) + b -> out(B,Lseg,8) fp32
// one wave per row; W preloaded into 96 regs/lane (c = lane + 64k, k<12)
// ---------------------------------------------------------------------------
__global__ __launch_bounds__(256) void proj_kernel(
    const float* __restrict__ x, const float* __restrict__ W,
    const float* __restrict__ bias, float* __restrict__ out,
    int Lseg, int segoff)
{
  const int tid  = threadIdx.x;
  const int lane = tid & 63;
  const int wid  = tid >> 6;
  const int b    = blockIdx.y;

  float wreg[12][8];
#pragma unroll
  for (int k = 0; k < 12; ++k) {
    const int c = lane + 64 * k;
    const float4 a = *reinterpret_cast<const float4*>(W + (size_t)c * 8);
    const float4 d4 = *reinterpret_cast<const float4*>(W + (size_t)c * 8 + 4);
    wreg[k][0]=a.x; wreg[k][1]=a.y; wreg[k][2]=a.z; wreg[k][3]=a.w;
    wreg[k][4]=d4.x; wreg[k][5]=d4.y; wreg[k][6]=d4.z; wreg[k][7]=d4.w;
  }

  const int l0 = blockIdx.x * 64 + wid * 16;
  const float* xb = x + ((size_t)b * LT + segoff) * CIN;
  float* ob = out + (size_t)b * Lseg * HC;

  for (int r = 0; r < 16; ++r) {
    const int l = l0 + r;
    const float* xr = xb + (size_t)l * CIN + lane;
    float acc[8] = {0.f,0.f,0.f,0.f,0.f,0.f,0.f,0.f};
#pragma unroll
    for (int k = 0; k < 12; ++k) {
      const float xv = xr[64 * k];
#pragma unroll
      for (int d = 0; d < 8; ++d) acc[d] = fmaf(xv, wreg[k][d], acc[d]);
    }
#pragma unroll
    for (int d = 0; d < 8; ++d) {
      float v = acc[d];
#pragma unroll
      for (int off = 32; off > 0; off >>= 1) v += __shfl_xor(v, off, 64);
      acc[d] = v;
    }
    if (lane == 0) {
#pragma unroll
      for (int d = 0; d < 8; ++d)
        ob[(size_t)l * HC + d] = acc[d] + bias[d];
    }
  }
}

// ---------------------------------------------------------------------------
// K2: flash attention, D=8. O[b,i,:] = softmax_j(Q[b,i]·K[b,j]) @ K[b]
// block = 1024 thr (16 waves), wave owns 4 query rows; K chunked by 1024 rows
// staged TRANSPOSED in LDS (kv[d][j]) -> conflict-free b32 reads.
// ---------------------------------------------------------------------------
__global__ __launch_bounds__(1024) void attn_kernel(
    const float* __restrict__ Q, const float* __restrict__ K,
    float* __restrict__ O, int Lq, int Lk)
{
  __shared__ float kvs[8 * 1024]; // 32 KB, [d][j]
  const int tid  = threadIdx.x;
  const int lane = tid & 63;
  const int wid  = tid >> 6;
  const int b    = blockIdx.y;
  const int q0   = blockIdx.x * 64 + wid * 4;

  const float* Qb = Q + ((size_t)b * Lq + q0) * HC;
  float q[4][8];
#pragma unroll
  for (int r = 0; r < 4; ++r) {
    const float4 a = *reinterpret_cast<const float4*>(Qb + r * 8);
    const float4 c = *reinterpret_cast<const float4*>(Qb + r * 8 + 4);
    q[r][0]=a.x; q[r][1]=a.y; q[r][2]=a.z; q[r][3]=a.w;
    q[r][4]=c.x; q[r][5]=c.y; q[r][6]=c.z; q[r][7]=c.w;
  }
  float M[4]   = {-INFINITY,-INFINITY,-INFINITY,-INFINITY};
  float sum[4] = {0.f,0.f,0.f,0.f};
  float acc[4][8];
#pragma unroll
  for (int r = 0; r < 4; ++r)
#pragma unroll
    for (int d = 0; d < 8; ++d) acc[r][d] = 0.f;

  const float* Kb = K + (size_t)b * Lk * HC;

  for (int c0 = 0; c0 < Lk; c0 += 1024) {
    const int clen = min(1024, Lk - c0);
    __syncthreads();
    if (tid < clen) {
      const float* kr = Kb + (size_t)(c0 + tid) * HC;
      const float4 a = *reinterpret_cast<const float4*>(kr);
      const float4 c = *reinterpret_cast<const float4*>(kr + 4);
      kvs[0*1024+tid]=a.x; kvs[1*1024+tid]=a.y; kvs[2*1024+tid]=a.z; kvs[3*1024+tid]=a.w;
      kvs[4*1024+tid]=c.x; kvs[5*1024+tid]=c.y; kvs[6*1024+tid]=c.z; kvs[7*1024+tid]=c.w;
    }
    __syncthreads();
    const int iters = clen >> 6;

    float cm[4] = {-INFINITY,-INFINITY,-INFINITY,-INFINITY};
    for (int it = 0; it < iters; ++it) {
      const int j = it * 64 + lane;
      float kx[8];
#pragma unroll
      for (int d = 0; d < 8; ++d) kx[d] = kvs[d * 1024 + j];
#pragma unroll
      for (int r = 0; r < 4; ++r) {
        float s = 0.f;
#pragma unroll
        for (int d = 0; d < 8; ++d) s = fmaf(q[r][d], kx[d], s);
        cm[r] = fmaxf(cm[r], s);
      }
    }
#pragma unroll
    for (int r = 0; r < 4; ++r) {
#pragma unroll
      for (int off = 32; off > 0; off >>= 1)
        cm[r] = fmaxf(cm[r], __shfl_xor(cm[r], off, 64));
      const float Mn = fmaxf(M[r], cm[r]);
      const float alpha = __expf(M[r] - Mn); // first chunk: exp(-inf)=0
      sum[r] *= alpha;
#pragma unroll
      for (int d = 0; d < 8; ++d) acc[r][d] *= alpha;
      M[r] = Mn;
    }
    for (int it = 0; it < iters; ++it) {
      const int j = it * 64 + lane;
      float kx[8];
#pragma unroll
      for (int d = 0; d < 8; ++d) kx[d] = kvs[d * 1024 + j];
#pragma unroll
      for (int r = 0; r < 4; ++r) {
        float s = 0.f;
#pragma unroll
        for (int d = 0; d < 8; ++d) s = fmaf(q[r][d], kx[d], s);
        const float p = __expf(s - M[r]);
        sum[r] += p;
#pragma unroll
        for (int d = 0; d < 8; ++d) acc[r][d] = fmaf(p, kx[d], acc[r][d]);
      }
    }
  }

#pragma unroll
  for (int r = 0; r < 4; ++r) {
#pragma unroll
    for (int off = 32; off > 0; off >>= 1) sum[r] += __shfl_xor(sum[r], off, 64);
#pragma unroll
    for (int d = 0; d < 8; ++d) {
      float v = acc[r][d];
#pragma unroll
      for (int off = 32; off > 0; off >>= 1) v += __shfl_xor(v, off, 64);
      acc[r][d] = v;
    }
  }
  if (lane == 0) {
    float* ob = O + ((size_t)b * Lq + q0) * HC;
#pragma unroll
    for (int r = 0; r < 4; ++r) {
      const float inv = 1.f / sum[r];
#pragma unroll
      for (int d = 0; d < 8; ++d) ob[r * 8 + d] = acc[r][d] * inv;
    }
  }
}

// ---------------------------------------------------------------------------
// K3: O[b,l,d] = softmax_l(T[b,:,d])[l] * T[b,l,d] + A[b,l,d]
// one block per (b,d) column
// ---------------------------------------------------------------------------
__global__ __launch_bounds__(256) void fovea_kernel(
    const float* __restrict__ T, const float* __restrict__ A,
    float* __restrict__ O, int L)
{
  const int tid  = threadIdx.x;
  const int lane = tid & 63;
  const int wid  = tid >> 6;
  const int b = blockIdx.x >> 3;
  const int d = blockIdx.x & 7;
  const float* t = T + (size_t)b * L * HC + d;
  const float* a = A + (size_t)b * L * HC + d;
  float* o = O + (size_t)b * L * HC + d;
  __shared__ float redm[4], reds[4];

  float m = -INFINITY;
  for (int l = tid; l < L; l += 256) m = fmaxf(m, t[(size_t)l * HC]);
#pragma unroll
  for (int off = 32; off > 0; off >>= 1) m = fmaxf(m, __shfl_xor(m, off, 64));
  if (lane == 0) redm[wid] = m;
  __syncthreads();
  const float Mx = fmaxf(fmaxf(redm[0], redm[1]), fmaxf(redm[2], redm[3]));

  float s = 0.f;
  for (int l = tid; l < L; l += 256) s += __expf(t[(size_t)l * HC] - Mx);
#pragma unroll
  for (int off = 32; off > 0; off >>= 1) s += __shfl_xor(s, off, 64);
  if (lane == 0) reds[wid] = s;
  __syncthreads();
  const float inv = 1.f / (reds[0] + reds[1] + reds[2] + reds[3]);

  for (int l = tid; l < L; l += 256) {
    const float v = t[(size_t)l * HC];
    o[(size_t)l * HC] = __expf(v - Mx) * inv * v + a[(size_t)l * HC];
  }
}

// ---------------------------------------------------------------------------
// K4: XO(B,L,8) fp32 @ W(8,768) + b -> out(B,768,L) fp32 (transposed write)
// block (64,4): tx along l (coalesced stores), each thread owns 4 c values
// ---------------------------------------------------------------------------
__global__ __launch_bounds__(256) void outproj_kernel(
    const float* __restrict__ XO, const float* __restrict__ W,
    const float* __restrict__ bias, float* __restrict__ out,
    int L, int nj)
{
  const int tx = threadIdx.x;
  const int ty = threadIdx.y;
  const int b  = blockIdx.z;
  const int c0 = blockIdx.y * 16;
  const int l0 = blockIdx.x * (nj * 64);

  float w[4][8], bv[4];
#pragma unroll
  for (int k = 0; k < 4; ++k) {
    const int c = c0 + ty * 4 + k;
#pragma unroll
    for (int d = 0; d < 8; ++d) w[k][d] = W[d * 768 + c];
    bv[k] = bias[c];
  }

  for (int j = 0; j < nj; ++j) {
    const int l = l0 + j * 64 + tx;
    const float* xr = XO + ((size_t)b * L + l) * HC;
    const float4 a  = *reinterpret_cast<const float4*>(xr);
    const float4 c4 = *reinterpret_cast<const float4*>(xr + 4);
    const float qv[8] = {a.x, a.y, a.z, a.w, c4.x, c4.y, c4.z, c4.w};
#pragma unroll
    for (int k = 0; k < 4; ++k) {
      float acc = bv[k];
#pragma unroll
      for (int d = 0; d < 8; ++d) acc = fmaf(qv[d], w[k][d], acc);
      out[((size_t)b * 768 + (c0 + ty * 4 + k)) * L + l] = acc;
    }
  }
}

// ---------------------------------------------------------------------------
extern "C" void kernel_launch(void* const* d_in, const int* in_sizes, int n_in,
                              void* d_out, int out_size, void* d_ws, size_t ws_size,
                              hipStream_t stream)
{
  const float* x   = (const float*)d_in[0];
  const float* W00 = (const float*)d_in[1];
  const float* b00 = (const float*)d_in[2];
  const float* W01 = (const float*)d_in[3];
  const float* b01 = (const float*)d_in[4];
  const float* W1  = (const float*)d_in[5];
  const float* b1  = (const float*)d_in[6];
  const float* W2  = (const float*)d_in[7];
  const float* b2  = (const float*)d_in[8];
  float* out = (float*)d_out;

  float* ws   = (float*)d_ws;
  float* x0t  = ws;                        // 16*1024*8 = 131072
  float* x1t  = x0t  + (size_t)16*1024*8;  // 16*3136*8 = 401408
  float* x0_1 = x1t  + (size_t)16*3136*8;
  float* x1_0 = x0_1 + (size_t)16*1024*8;
  float* x0o  = x1_0 + (size_t)16*3136*8;
  float* x1o  = x0o  + (size_t)16*1024*8;  // total 1,597,440 fp32 = 6.4 MB

  proj_kernel<<<dim3(16, 16), 256, 0, stream>>>(x, W00, b00, x0t, 1024, 0);
  proj_kernel<<<dim3(49, 16), 256, 0, stream>>>(x, W01, b01, x1t, 3136, 1024);

  attn_kernel<<<dim3(16, 16), 1024, 0, stream>>>(x0t, x1t, x0_1, 1024, 3136);
  attn_kernel<<<dim3(49, 16), 1024, 0, stream>>>(x1t, x0t, x1_0, 3136, 1024);

  fovea_kernel<<<128, 256, 0, stream>>>(x0t, x0_1, x0o, 1024);
  fovea_kernel<<<128, 256, 0, stream>>>(x1_0, x1t, x1o, 3136);

  outproj_kernel<<<dim3(4, 48, 16), dim3(64, 4), 0, stream>>>(
      x0o, W1, b1, out, 1024, 4);
  outproj_kernel<<<dim3(7, 48, 16), dim3(64, 4), 0, stream>>>(
      x1o, W2, b2, out + (size_t)16 * 768 * 1024, 3136, 7);
}